// Round 1
// baseline (119.638 us; speedup 1.0000x reference)
//
#include <hip/hip_runtime.h>

#define HOP 256
#define CUT 513
#define T_FRAMES 1021
#define N_SAMPLES 262144
#define BATCH 16
#define TILE_T 12
#define NBLK_PER_B 86   // ceil(1021/12)

// pad every 32 floats/doubles by 1 element to spread LDS banks
__device__ __forceinline__ int swz(int i) { return i + (i >> 5); }
// base-4 digit reversal of a 10-bit index (involution)
__device__ __forceinline__ int drev(int p) {
    return ((p & 3) << 8) | (((p >> 2) & 3) << 6) | (((p >> 4) & 3) << 4)
         | (((p >> 6) & 3) << 2) | ((p >> 8) & 3);
}

__global__ __launch_bounds__(256, 2) void stft_fft_kernel(
    const float* __restrict__ x,
    const float* __restrict__ basis,
    float* __restrict__ out)
{
    // fp64 FFT work buffers (swizzled, 1024 pts -> 1056 slots)
    __shared__ double re[1056];
    __shared__ double im[1056];
    // staged outputs: odd leading stride 513 -> conflict-free column access
    __shared__ float smag[TILE_T][CUT];
    __shared__ float sph[TILE_T][CUT];
    // fp64 twiddle table W_1024^j = exp(-2*pi*i*j/1024), j in [0,768), swizzled
    __shared__ double twc[792];
    __shared__ double tws[792];
    __shared__ double redA[4], redB[4];

    const int tid  = threadIdx.x;
    const int b    = blockIdx.x / NBLK_PER_B;
    const int tile = blockIdx.x % NBLK_PER_B;
    const int t0   = tile * TILE_T;
    const int cnt  = min(TILE_T, T_FRAMES - t0);

    // build twiddles once per block (fp64 sincos; covered by first barrier)
    for (int j = tid; j < 768; j += 256) {
        double th = (6.2831853071795864769252867665590057684 / 1024.0) * (double)j;
        twc[swz(j)] = cos(th);
        tws[swz(j)] = sin(th);
    }

    const float* xb    = x + (size_t)b * N_SAMPLES;
    const float* wrow  = basis;                 // row 0 of basis == Hann window
    const float* nyrow = basis + 1025 * 1024;   // imag Nyquist row (tiny values)

    const int npairs = (cnt + 1) >> 1;
    for (int u = 0; u < npairs; ++u) {
        const int fa = 2 * u, fb = fa + 1;
        const bool has_b = (fb < cnt);
        const int ta = t0 + fa;
        const float* pa = xb + (size_t)ta * HOP;

        // load two real frames packed as one complex signal; accumulate the
        // explicit Nyquist-imag dot (matches reference's tiny-nonzero row)
        double accA = 0.0, accB = 0.0;
        #pragma unroll
        for (int j = 0; j < 4; ++j) {
            int n = tid + 256 * j;
            float w  = wrow[n];
            float av = pa[n];
            float bv = has_b ? pa[n + HOP] : 0.0f;
            re[swz(n)] = (double)w * (double)av;
            im[swz(n)] = (double)w * (double)bv;
            float bn = nyrow[n];
            accA += (double)bn * (double)av;
            accB += (double)bn * (double)bv;
        }
        #pragma unroll
        for (int off = 32; off > 0; off >>= 1) {
            accA += __shfl_down(accA, off);
            accB += __shfl_down(accB, off);
        }
        if ((tid & 63) == 0) { redA[tid >> 6] = accA; redB[tid >> 6] = accB; }
        __syncthreads();

        // 5 radix-4 DIF stages, in place; output lands digit-reversed
        #pragma unroll
        for (int s = 0; s < 5; ++s) {
            const int m4 = 1024 >> (2 * s);
            const int q  = m4 >> 2;
            const int n  = tid & (q - 1);
            const int base = (tid >> (8 - 2 * s)) * m4 + n;
            const int e  = n << (2 * s);          // n * 4^s  (< 256)
            const int i0 = swz(base), i1 = swz(base + q);
            const int i2 = swz(base + 2 * q), i3 = swz(base + 3 * q);
            double ar = re[i0], ai = im[i0], br = re[i1], bi = im[i1];
            double cr = re[i2], ci = im[i2], dr = re[i3], di = im[i3];
            double t0r = ar + cr, t0i = ai + ci, t1r = ar - cr, t1i = ai - ci;
            double t2r = br + dr, t2i = bi + di, t3r = br - dr, t3i = bi - di;
            double y0r = t0r + t2r, y0i = t0i + t2i;
            double y2r = t0r - t2r, y2i = t0i - t2i;
            double y1r = t1r + t3i, y1i = t1i - t3r;   // (t1 - i*t3)
            double y3r = t1r - t3i, y3i = t1i + t3r;   // (t1 + i*t3)
            double c1 = twc[swz(e)],     s1 = tws[swz(e)];
            double c2 = twc[swz(2 * e)], s2 = tws[swz(2 * e)];
            double c3 = twc[swz(3 * e)], s3 = tws[swz(3 * e)];
            re[i0] = y0r;                 im[i0] = y0i;
            re[i1] = y1r * c1 + y1i * s1; im[i1] = y1i * c1 - y1r * s1;
            re[i2] = y2r * c2 + y2i * s2; im[i2] = y2i * c2 - y2r * s2;
            re[i3] = y3r * c3 + y3i * s3; im[i3] = y3i * c3 - y3r * s3;
            __syncthreads();
        }

        // unpack the two real spectra from the packed complex FFT
        const double iNyA = redA[0] + redA[1] + redA[2] + redA[3];
        const double iNyB = redB[0] + redB[1] + redB[2] + redB[3];
        for (int k = tid; k <= 512; k += 256) {
            int p1 = swz(drev(k));
            int p2 = swz(drev((1024 - k) & 1023));
            double zr1 = re[p1], zi1 = im[p1];
            double zr2 = re[p2], zi2 = im[p2];
            double arD = 0.5 * (zr1 + zr2), aiD = 0.5 * (zi1 - zi2);
            double brD = 0.5 * (zi1 + zi2), biD = 0.5 * (zr2 - zr1);
            if (k == 512) { aiD = iNyA; biD = iNyB; }  // match basis row 1025
            float arf = (float)arD, aif = (float)aiD;
            smag[fa][k] = sqrtf(arf * arf + aif * aif);
            sph[fa][k]  = atan2f(aif, arf);
            if (has_b) {
                float brf = (float)brD, bif = (float)biD;
                smag[fb][k] = sqrtf(brf * brf + bif * bif);
                sph[fb][k]  = atan2f(bif, brf);
            }
        }
        __syncthreads();
    }

    // coalesced write-out: consecutive threads cover consecutive t
    float* omag = out + (size_t)b * CUT * T_FRAMES;
    float* oph  = omag + (size_t)BATCH * CUT * T_FRAMES;
    const int total = CUT * cnt;
    for (int flat = tid; flat < total; flat += 256) {
        int k  = flat / cnt;
        int tt = flat - k * cnt;
        size_t g = (size_t)k * T_FRAMES + (size_t)(t0 + tt);
        omag[g] = smag[tt][k];
        oph[g]  = sph[tt][k];
    }
}

extern "C" void kernel_launch(void* const* d_in, const int* in_sizes, int n_in,
                              void* d_out, int out_size, void* d_ws, size_t ws_size,
                              hipStream_t stream) {
    (void)in_sizes; (void)n_in; (void)d_ws; (void)ws_size; (void)out_size;
    const float* x     = (const float*)d_in[0];
    const float* basis = (const float*)d_in[1];
    float* out = (float*)d_out;
    dim3 grid(BATCH * NBLK_PER_B);   // 16 * 86 = 1376
    dim3 block(256);
    stft_fft_kernel<<<grid, block, 0, stream>>>(x, basis, out);
}

// Round 2
// 118.740 us; speedup vs baseline: 1.0076x; 1.0076x over previous
//
#include <hip/hip_runtime.h>

#define HOP 256
#define CUT 513
#define T_FRAMES 1021
#define N_SAMPLES 262144
#define BATCH 16
#define TILE_T 16
#define NBLK_PER_B 64          // ceil(1021/16)
#define NPAIR 8
#define NWG (BATCH * NBLK_PER_B)   // 1024, divisible by 8 XCDs

// pad every 32 doubles by 1 to spread LDS banks for strided butterfly access
__device__ __forceinline__ int swz(int i) { return i + (i >> 5); }
// base-4 digit reversal of a 10-bit index (involution)
__device__ __forceinline__ int drev(int p) {
    return ((p & 3) << 8) | (((p >> 2) & 3) << 6) | (((p >> 4) & 3) << 4)
         | (((p >> 6) & 3) << 2) | ((p >> 8) & 3);
}

__global__ __launch_bounds__(256, 3) void stft_fft_kernel(
    const float* __restrict__ x,
    const float* __restrict__ basis,
    float* __restrict__ out)
{
    // LDS union:
    //   phase 1 (FFT rounds): re[1056] + im[1056] + tc[256] + ts[256] doubles = 20992 B
    //   phase 2 (write-out):  obuf float[513][17] = 34884 B
    __shared__ __align__(16) unsigned char smem[34896];
    __shared__ double redRA[4], redRB[4], redIA[4], redIB[4];
    __shared__ float k512m[TILE_T], k512p[TILE_T];

    double* re = (double*)smem;
    double* im = re + 1056;
    double* tc = im + 1056;
    double* ts = tc + 256;
    float* obuf = (float*)smem;          // [513][17], stride 17 -> conflict-free

    const int tid = threadIdx.x;
    // XCD-chunked bijective block swizzle: each XCD gets 128 consecutive tiles
    const int wid  = (blockIdx.x & 7) * (NWG / 8) + (blockIdx.x >> 3);
    const int b    = wid / NBLK_PER_B;
    const int tile = wid % NBLK_PER_B;
    const int t0   = tile * TILE_T;
    const int cnt  = min(TILE_T, T_FRAMES - t0);   // 16, or 13 on the last tile

    // 256-entry fp64 twiddle base table; W^j for j in [0,256)
    {
        double th = (6.2831853071795864769252867665590057684 / 1024.0) * (double)tid;
        tc[tid] = cos(th);
        ts[tid] = sin(th);
    }

    const float* xb    = x + (size_t)b * N_SAMPLES;
    const float* wrow  = basis;                         // row 0 == Hann window
    const float* r512  = basis + (size_t)512 * 1024;    // real Nyquist row
    const float* r1025 = basis + (size_t)1025 * 1024;   // imag Nyquist row (tiny)

    // register-staged outputs: [pair][frame a/b][k-slot (tid, tid+256)]
    float rm[NPAIR][2][2];
    float rp[NPAIR][2][2];

    #pragma unroll
    for (int u = 0; u < NPAIR; ++u) {
        const int fa = 2 * u, fb = fa + 1;
        if (fa < cnt) {                       // block-uniform guard
            const bool has_b = (fb < cnt);
            const float* pa = xb + (size_t)(t0 + fa) * HOP;

            // load two real frames packed as one complex signal; explicit fp64
            // dots with basis rows 512 (real Nyq) and 1025 (imag Nyq)
            double aR = 0.0, bR = 0.0, aI = 0.0, bI = 0.0;
            #pragma unroll
            for (int jj = 0; jj < 4; ++jj) {
                int n = tid + 256 * jj;
                float w  = wrow[n];
                float av = pa[n];
                float bv = has_b ? pa[n + HOP] : 0.0f;
                re[swz(n)] = (double)w * (double)av;
                im[swz(n)] = (double)w * (double)bv;
                float c5 = r512[n], c10 = r1025[n];
                aR += (double)c5  * (double)av;
                bR += (double)c5  * (double)bv;
                aI += (double)c10 * (double)av;
                bI += (double)c10 * (double)bv;
            }
            #pragma unroll
            for (int off = 32; off > 0; off >>= 1) {
                aR += __shfl_down(aR, off); bR += __shfl_down(bR, off);
                aI += __shfl_down(aI, off); bI += __shfl_down(bI, off);
            }
            if ((tid & 63) == 0) {
                int w4 = tid >> 6;
                redRA[w4] = aR; redRB[w4] = bR; redIA[w4] = aI; redIB[w4] = bI;
            }
            __syncthreads();

            // 5 radix-4 DIF stages in place (output digit-reversed)
            for (int s = 0; s < 5; ++s) {
                const int m4 = 1024 >> (2 * s);
                const int q  = m4 >> 2;
                const int n  = tid & (q - 1);
                const int base = (tid >> (8 - 2 * s)) * m4 + n;
                const int e  = n << (2 * s);          // always < 256
                const int i0 = swz(base), i1 = swz(base + q);
                const int i2 = swz(base + 2 * q), i3 = swz(base + 3 * q);
                double ar = re[i0], ai = im[i0], br = re[i1], bi = im[i1];
                double cr = re[i2], ci = im[i2], dr = re[i3], di = im[i3];
                double t0r = ar + cr, t0i = ai + ci, t1r = ar - cr, t1i = ai - ci;
                double t2r = br + dr, t2i = bi + di, t3r = br - dr, t3i = bi - di;
                double y0r = t0r + t2r, y0i = t0i + t2i;
                double y2r = t0r - t2r, y2i = t0i - t2i;
                double y1r = t1r + t3i, y1i = t1i - t3r;   // (t1 - i*t3)
                double y3r = t1r - t3i, y3i = t1i + t3r;   // (t1 + i*t3)
                // twiddles W^e, W^2e, W^3e from the 256-entry quarter table
                double c1 = tc[e], s1 = ts[e];
                int e2 = 2 * e;  int r2 = e2 & 255;
                double c2b = tc[r2], s2b = ts[r2];
                double c2 = (e2 < 256) ? c2b : -s2b;
                double s2 = (e2 < 256) ? s2b :  c2b;
                int e3 = 3 * e;  int r3 = e3 & 255;  int q3 = e3 >> 8;
                double c3b = tc[r3], s3b = ts[r3];
                double c3 = (q3 == 0) ? c3b : ((q3 == 1) ? -s3b : -c3b);
                double s3 = (q3 == 0) ? s3b : ((q3 == 1) ?  c3b : -s3b);
                re[i0] = y0r;                 im[i0] = y0i;
                re[i1] = y1r * c1 + y1i * s1; im[i1] = y1i * c1 - y1r * s1;
                re[i2] = y2r * c2 + y2i * s2; im[i2] = y2i * c2 - y2r * s2;
                re[i3] = y3r * c3 + y3i * s3; im[i3] = y3i * c3 - y3r * s3;
                __syncthreads();
            }

            // k=512 handled by explicit dots (matches reference rows 512/1025)
            if (tid < 2) {
                double rr = (tid == 0) ? (redRA[0] + redRA[1] + redRA[2] + redRA[3])
                                       : (redRB[0] + redRB[1] + redRB[2] + redRB[3]);
                double ii = (tid == 0) ? (redIA[0] + redIA[1] + redIA[2] + redIA[3])
                                       : (redIB[0] + redIB[1] + redIB[2] + redIB[3]);
                float rf = (float)rr, iff = (float)ii;
                k512m[fa + tid] = sqrtf(rf * rf + iff * iff);
                k512p[fa + tid] = atan2f(iff, rf);
            }

            // unpack the two real spectra for k in [0,512) -> registers
            #pragma unroll
            for (int j = 0; j < 2; ++j) {
                int k  = tid + 256 * j;
                int p1 = swz(drev(k));
                int p2 = swz(drev((1024 - k) & 1023));
                double zr1 = re[p1], zi1 = im[p1];
                double zr2 = re[p2], zi2 = im[p2];
                float arf = (float)(0.5 * (zr1 + zr2));
                float aif = (float)(0.5 * (zi1 - zi2));
                float brf = (float)(0.5 * (zi1 + zi2));
                float bif = (float)(0.5 * (zr2 - zr1));
                rm[u][0][j] = sqrtf(arf * arf + aif * aif);
                rp[u][0][j] = atan2f(aif, arf);
                rm[u][1][j] = sqrtf(brf * brf + bif * bif);
                rp[u][1][j] = atan2f(bif, brf);
            }
        }
        __syncthreads();   // readers of re/im done before next round / obuf reuse
    }

    float* omag = out + (size_t)b * CUT * T_FRAMES;
    float* oph  = omag + (size_t)BATCH * CUT * T_FRAMES;

    // ---- pass 1: magnitude ----
    #pragma unroll
    for (int u = 0; u < NPAIR; ++u) {
        if (2 * u < cnt) {
            obuf[tid * 17 + 2 * u]               = rm[u][0][0];
            obuf[(tid + 256) * 17 + 2 * u]       = rm[u][0][1];
            obuf[tid * 17 + 2 * u + 1]           = rm[u][1][0];
            obuf[(tid + 256) * 17 + 2 * u + 1]   = rm[u][1][1];
        }
    }
    __syncthreads();
    for (int idx = tid; idx < 512 * 16; idx += 256) {
        int k = idx >> 4, tt = idx & 15;
        if (tt < cnt) omag[(size_t)k * T_FRAMES + t0 + tt] = obuf[k * 17 + tt];
    }
    if (tid < cnt) omag[(size_t)512 * T_FRAMES + t0 + tid] = k512m[tid];
    __syncthreads();

    // ---- pass 2: phase ----
    #pragma unroll
    for (int u = 0; u < NPAIR; ++u) {
        if (2 * u < cnt) {
            obuf[tid * 17 + 2 * u]               = rp[u][0][0];
            obuf[(tid + 256) * 17 + 2 * u]       = rp[u][0][1];
            obuf[tid * 17 + 2 * u + 1]           = rp[u][1][0];
            obuf[(tid + 256) * 17 + 2 * u + 1]   = rp[u][1][1];
        }
    }
    __syncthreads();
    for (int idx = tid; idx < 512 * 16; idx += 256) {
        int k = idx >> 4, tt = idx & 15;
        if (tt < cnt) oph[(size_t)k * T_FRAMES + t0 + tt] = obuf[k * 17 + tt];
    }
    if (tid < cnt) oph[(size_t)512 * T_FRAMES + t0 + tid] = k512p[tid];
}

extern "C" void kernel_launch(void* const* d_in, const int* in_sizes, int n_in,
                              void* d_out, int out_size, void* d_ws, size_t ws_size,
                              hipStream_t stream) {
    (void)in_sizes; (void)n_in; (void)d_ws; (void)ws_size; (void)out_size;
    const float* x     = (const float*)d_in[0];
    const float* basis = (const float*)d_in[1];
    float* out = (float*)d_out;
    dim3 grid(NWG);      // 1024
    dim3 block(256);
    stft_fft_kernel<<<grid, block, 0, stream>>>(x, basis, out);
}

// Round 3
// 100.719 us; speedup vs baseline: 1.1878x; 1.1789x over previous
//
#include <hip/hip_runtime.h>

#define HOP 256
#define CUT 513
#define T_FRAMES 1021
#define N_SAMPLES 262144
#define BATCH 16
#define NPAIR_PER_B 511                 // ceil(1021/2); last pair is a lone frame
#define NWG (BATCH * NPAIR_PER_B)       // 8176, divisible by 8 XCDs

// XOR swizzle: spreads every radix-4 butterfly stage's b128 accesses
// conflict-free across the 8 quad-bank groups (verified per-stage analytically)
__device__ __forceinline__ int pswz(int i) { return i ^ ((i >> 3) & 7); }
// base-4 digit reversal of a 10-bit index (involution)
__device__ __forceinline__ int drev(int p) {
    return ((p & 3) << 8) | (((p >> 2) & 3) << 6) | (((p >> 4) & 3) << 4)
         | (((p >> 6) & 3) << 2) | ((p >> 8) & 3);
}

__global__ __launch_bounds__(256, 6) void stft_fft_kernel(
    const float* __restrict__ x,
    const float* __restrict__ basis,
    float* __restrict__ out)
{
    __shared__ double2 z[1024];      // interleaved (re,im), XOR-swizzled
    __shared__ double2 tw[256];      // (cos, sin) of 2*pi*j/1024
    __shared__ double redRA[4], redRB[4], redIA[4], redIB[4];

    const int tid = threadIdx.x;
    // XCD-chunked bijective swizzle: 1022 consecutive pairs per XCD
    const int wid = (blockIdx.x & 7) * (NWG / 8) + (blockIdx.x >> 3);
    const int b   = wid / NPAIR_PER_B;
    const int pr  = wid % NPAIR_PER_B;
    const int t0  = 2 * pr;
    const bool has_b = (t0 + 1 < T_FRAMES);   // block-uniform

    // 256-entry fp64 twiddle quarter table
    {
        double th = (6.2831853071795864769252867665590057684 / 1024.0) * (double)tid;
        tw[tid] = make_double2(cos(th), sin(th));
    }

    const float* pa    = x + (size_t)b * N_SAMPLES + (size_t)t0 * HOP;
    const float* wrow  = basis;                         // row 0 == Hann window
    const float* r512  = basis + (size_t)512 * 1024;    // real Nyquist row
    const float* r1025 = basis + (size_t)1025 * 1024;   // imag Nyquist row

    // load two overlapping frames (1280 samples) + basis rows
    float v[5], wv[4], c5v[4], c10v[4];
    #pragma unroll
    for (int j = 0; j < 4; ++j) {
        v[j]    = pa[tid + 256 * j];
        wv[j]   = wrow[tid + 256 * j];
        c5v[j]  = r512[tid + 256 * j];
        c10v[j] = r1025[tid + 256 * j];
    }
    v[4] = has_b ? pa[tid + 1024] : 0.0f;

    double aR = 0.0, bR = 0.0, aI = 0.0, bI = 0.0;
    #pragma unroll
    for (int j = 0; j < 4; ++j) {
        int n = tid + 256 * j;
        double av = (double)v[j];
        double bv = has_b ? (double)v[j + 1] : 0.0;
        double w  = (double)wv[j];
        z[pswz(n)] = make_double2(w * av, w * bv);
        aR += (double)c5v[j]  * av;  bR += (double)c5v[j]  * bv;
        aI += (double)c10v[j] * av;  bI += (double)c10v[j] * bv;
    }
    #pragma unroll
    for (int off = 32; off > 0; off >>= 1) {
        aR += __shfl_down(aR, off); bR += __shfl_down(bR, off);
        aI += __shfl_down(aI, off); bI += __shfl_down(bI, off);
    }
    if ((tid & 63) == 0) {
        int w4 = tid >> 6;
        redRA[w4] = aR; redRB[w4] = bR; redIA[w4] = aI; redIB[w4] = bI;
    }
    __syncthreads();

    // 5 radix-4 DIF stages in place (output digit-reversed)
    #pragma unroll
    for (int s = 0; s < 5; ++s) {
        const int m4 = 1024 >> (2 * s);
        const int q  = m4 >> 2;
        const int n  = tid & (q - 1);
        const int base = (tid >> (8 - 2 * s)) * m4 + n;
        const int e  = n << (2 * s);          // always < 256
        const int i0 = pswz(base),         i1 = pswz(base + q);
        const int i2 = pswz(base + 2 * q), i3 = pswz(base + 3 * q);
        double2 A = z[i0], Bz = z[i1], C = z[i2], D = z[i3];
        double t0r = A.x + C.x,  t0i = A.y + C.y;
        double t1r = A.x - C.x,  t1i = A.y - C.y;
        double t2r = Bz.x + D.x, t2i = Bz.y + D.y;
        double t3r = Bz.x - D.x, t3i = Bz.y - D.y;
        double y0r = t0r + t2r, y0i = t0i + t2i;
        double y2r = t0r - t2r, y2i = t0i - t2i;
        double y1r = t1r + t3i, y1i = t1i - t3r;   // (t1 - i*t3)
        double y3r = t1r - t3i, y3i = t1i + t3r;   // (t1 + i*t3)
        double2 T1 = tw[e];
        double c1 = T1.x, s1 = T1.y;
        int e2 = 2 * e;  int r2 = e2 & 255;
        double2 T2 = tw[r2];
        double c2 = (e2 < 256) ? T2.x : -T2.y;
        double s2 = (e2 < 256) ? T2.y :  T2.x;
        int e3 = 3 * e;  int r3 = e3 & 255;  int q3 = e3 >> 8;
        double2 T3 = tw[r3];
        double c3 = (q3 == 0) ? T3.x : ((q3 == 1) ? -T3.y : -T3.x);
        double s3 = (q3 == 0) ? T3.y : ((q3 == 1) ?  T3.x : -T3.y);
        z[i0] = make_double2(y0r, y0i);
        z[i1] = make_double2(y1r * c1 + y1i * s1, y1i * c1 - y1r * s1);
        z[i2] = make_double2(y2r * c2 + y2i * s2, y2i * c2 - y2r * s2);
        z[i3] = make_double2(y3r * c3 + y3i * s3, y3i * c3 - y3r * s3);
        __syncthreads();
    }

    float* omag = out + (size_t)b * CUT * T_FRAMES;
    float* oph  = omag + (size_t)BATCH * CUT * T_FRAMES;

    // unpack the two real spectra and write directly
    #pragma unroll
    for (int j = 0; j < 2; ++j) {
        int k  = tid + 256 * j;
        int p1 = pswz(drev(k));
        int p2 = pswz(drev((1024 - k) & 1023));
        double2 z1 = z[p1], z2 = z[p2];
        float arf = (float)(0.5 * (z1.x + z2.x));
        float aif = (float)(0.5 * (z1.y - z2.y));
        size_t g = (size_t)k * T_FRAMES + (size_t)t0;
        omag[g] = sqrtf(arf * arf + aif * aif);
        oph[g]  = atan2f(aif, arf);
        if (has_b) {
            float brf = (float)(0.5 * (z1.y + z2.y));
            float bif = (float)(0.5 * (z2.x - z1.x));
            omag[g + 1] = sqrtf(brf * brf + bif * bif);
            oph[g + 1]  = atan2f(bif, brf);
        }
    }
    if (tid == 0) {
        double rr = redRA[0] + redRA[1] + redRA[2] + redRA[3];
        double ii = redIA[0] + redIA[1] + redIA[2] + redIA[3];
        float rf = (float)rr, iff = (float)ii;
        size_t g = (size_t)512 * T_FRAMES + (size_t)t0;
        omag[g] = sqrtf(rf * rf + iff * iff);
        oph[g]  = atan2f(iff, rf);
        if (has_b) {
            double rr2 = redRB[0] + redRB[1] + redRB[2] + redRB[3];
            double ii2 = redIB[0] + redIB[1] + redIB[2] + redIB[3];
            float rf2 = (float)rr2, if2 = (float)ii2;
            omag[g + 1] = sqrtf(rf2 * rf2 + if2 * if2);
            oph[g + 1]  = atan2f(if2, rf2);
        }
    }
}

extern "C" void kernel_launch(void* const* d_in, const int* in_sizes, int n_in,
                              void* d_out, int out_size, void* d_ws, size_t ws_size,
                              hipStream_t stream) {
    (void)in_sizes; (void)n_in; (void)d_ws; (void)ws_size; (void)out_size;
    const float* x     = (const float*)d_in[0];
    const float* basis = (const float*)d_in[1];
    float* out = (float*)d_out;
    dim3 grid(NWG);     // 8176
    dim3 block(256);
    stft_fft_kernel<<<grid, block, 0, stream>>>(x, basis, out);
}

// Round 5
// 89.764 us; speedup vs baseline: 1.3328x; 1.1220x over previous
//
#include <hip/hip_runtime.h>

#define HOP 256
#define CUT 513
#define T_FRAMES 1021
#define N_SAMPLES 262144
#define BATCH 16
#define NPAIR_PER_B 511                 // ceil(1021/2); last pair is a lone frame
#define NWG (BATCH * NPAIR_PER_B)       // 8176, divisible by 8 XCDs

// XOR swizzle for double2 LDS arrays (slot = 16B granule, 8 per row)
__device__ __forceinline__ int pswz(int i) { return i ^ ((i >> 3) & 7); }
// 8-bit base-4 digit reversal (involution on [0,256))
__device__ __forceinline__ int drev8(int t) {
    return ((t & 3) << 6) | (((t >> 2) & 3) << 4) | (((t >> 4) & 3) << 2) | ((t >> 6) & 3);
}

__global__ __launch_bounds__(256, 6) void stft_fft_kernel(
    const float* __restrict__ x,
    const float* __restrict__ basis,
    float* __restrict__ out)
{
    __shared__ double2 z[1024];      // interleaved (re,im), XOR-swizzled
    __shared__ double2 tw[256];      // (cos, sin) of 2*pi*j/1024, XOR-swizzled
    __shared__ float redIA[4], redIB[4];

    const int tid = threadIdx.x;
    // XCD-chunked bijective swizzle: 1022 consecutive pairs per XCD
    const int wid = (blockIdx.x & 7) * (NWG / 8) + (blockIdx.x >> 3);
    const int b   = wid / NPAIR_PER_B;
    const int pr  = wid % NPAIR_PER_B;
    const int t0  = 2 * pr;
    const bool has_b = (t0 + 1 < T_FRAMES);   // block-uniform

    // ---- twiddle build: angle(j) = a*(pi/8) + 2*pi*m/1024, j = 64a + m.
    // Poly on x = 2*pi*m/1024 <= 0.3866 (trunc err ~2e-14), then EXACT
    // rotation by a*(pi/8) via fp64 constants. No sincos. ----
    {
        const int m = tid & 63, a = tid >> 6;
        double xx = (6.2831853071795864769252867665590057684 / 1024.0) * (double)m;
        double x2 = xx * xx;
        double cc = 1.0 + x2 * (-0.5 + x2 * (1.0/24.0 + x2 * (-1.0/720.0
                   + x2 * (1.0/40320.0 + x2 * (-1.0/3628800.0)))));
        double ss = xx * (1.0 + x2 * (-1.0/6.0 + x2 * (1.0/120.0 + x2 * (-1.0/5040.0
                   + x2 * (1.0/362880.0 + x2 * (-1.0/39916800.0))))));
        // cos/sin of a*pi/8 for a = 0..3
        double ca = (a == 0) ? 1.0
                  : (a == 1) ? 0.92387953251128675612818318939679
                  : (a == 2) ? 0.70710678118654752440084436210485
                             : 0.38268343236508977172845998403040;
        double sa = (a == 0) ? 0.0
                  : (a == 1) ? 0.38268343236508977172845998403040
                  : (a == 2) ? 0.70710678118654752440084436210485
                             : 0.92387953251128675612818318939679;
        tw[pswz(tid)] = make_double2(cc * ca - ss * sa, ss * ca + cc * sa);
    }

    const float* pa    = x + (size_t)b * N_SAMPLES + (size_t)t0 * HOP;
    const float* wrow  = basis;                         // row 0 == Hann window
    const float* r1025 = basis + (size_t)1025 * 1024;   // imag Nyquist row (tiny)

    // load two overlapping frames (1280 samples) + window + Nyquist-imag row
    float v[5], wv[4], cny[4];
    #pragma unroll
    for (int j = 0; j < 4; ++j) {
        v[j]   = pa[tid + 256 * j];
        wv[j]  = wrow[tid + 256 * j];
        cny[j] = r1025[tid + 256 * j];
    }
    v[4] = has_b ? pa[tid + 1024] : 0.0f;

    // pack 2 real frames into one complex signal; fp32 imag-Nyquist dots
    // (terms ~1e-13*x -> fp32 accumulation is sign-stable at the ~1e-12 scale)
    float aI = 0.0f, bI = 0.0f;
    #pragma unroll
    for (int j = 0; j < 4; ++j) {
        int n = tid + 256 * j;
        double av = (double)v[j];
        double bv = has_b ? (double)v[j + 1] : 0.0;
        double w  = (double)wv[j];
        z[pswz(n)] = make_double2(w * av, w * bv);
        aI += cny[j] * v[j];
        bI += has_b ? cny[j] * v[j + 1] : 0.0f;
    }
    #pragma unroll
    for (int off = 32; off > 0; off >>= 1) {
        aI += __shfl_down(aI, off);
        bI += __shfl_down(bI, off);
    }
    if ((tid & 63) == 0) { redIA[tid >> 6] = aI; redIB[tid >> 6] = bI; }
    __syncthreads();

    // ---- 4 radix-4 DIF stages through LDS ----
    #pragma unroll
    for (int s = 0; s < 4; ++s) {
        const int m4 = 1024 >> (2 * s);
        const int q  = m4 >> 2;
        const int n  = tid & (q - 1);
        const int base = (tid >> (8 - 2 * s)) * m4 + n;
        const int e  = n << (2 * s);          // always < 256
        const int i0 = pswz(base),         i1 = pswz(base + q);
        const int i2 = pswz(base + 2 * q), i3 = pswz(base + 3 * q);
        double2 A = z[i0], Bz = z[i1], C = z[i2], D = z[i3];
        double t0r = A.x + C.x,  t0i = A.y + C.y;
        double t1r = A.x - C.x,  t1i = A.y - C.y;
        double t2r = Bz.x + D.x, t2i = Bz.y + D.y;
        double t3r = Bz.x - D.x, t3i = Bz.y - D.y;
        double y0r = t0r + t2r, y0i = t0i + t2i;
        double y2r = t0r - t2r, y2i = t0i - t2i;
        double y1r = t1r + t3i, y1i = t1i - t3r;   // (t1 - i*t3)
        double y3r = t1r - t3i, y3i = t1i + t3r;   // (t1 + i*t3)
        double2 T1 = tw[pswz(e)];
        double c1 = T1.x, s1 = T1.y;
        int e2 = 2 * e;  int r2 = e2 & 255;
        double2 T2 = tw[pswz(r2)];
        double c2 = (e2 < 256) ? T2.x : -T2.y;
        double s2 = (e2 < 256) ? T2.y :  T2.x;
        int e3 = 3 * e;  int r3 = e3 & 255;  int q3 = e3 >> 8;
        double2 T3 = tw[pswz(r3)];
        double c3 = (q3 == 0) ? T3.x : ((q3 == 1) ? -T3.y : -T3.x);
        double s3 = (q3 == 0) ? T3.y : ((q3 == 1) ?  T3.x : -T3.y);
        z[i0] = make_double2(y0r, y0i);
        z[i1] = make_double2(y1r * c1 + y1i * s1, y1i * c1 - y1r * s1);
        z[i2] = make_double2(y2r * c2 + y2i * s2, y2i * c2 - y2r * s2);
        z[i3] = make_double2(y3r * c3 + y3i * s3, y3i * c3 - y3r * s3);
        __syncthreads();
    }

    // ---- stage 4 (q=1, e=0 -> no twiddle): consecutive reads, keep in regs.
    // Position 4t+c holds bin 256c + drev8(t) after DIF. ----
    double2 A = z[pswz(4 * tid + 0)];
    double2 Bz = z[pswz(4 * tid + 1)];
    double2 C = z[pswz(4 * tid + 2)];
    double2 D = z[pswz(4 * tid + 3)];
    double t0r = A.x + C.x,  t0i = A.y + C.y;
    double t1r = A.x - C.x,  t1i = A.y - C.y;
    double t2r = Bz.x + D.x, t2i = Bz.y + D.y;
    double t3r = Bz.x - D.x, t3i = Bz.y - D.y;
    double2 y0 = make_double2(t0r + t2r, t0i + t2i);   // bin r
    double2 y1 = make_double2(t1r + t3i, t1i - t3r);   // bin 256+r
    double2 y2 = make_double2(t0r - t2r, t0i - t2i);   // bin 512+r
    double2 y3 = make_double2(t1r - t3i, t1i + t3r);   // bin 768+r

    // exchange: write own 4 back in place (thread-private slots, no hazard)
    z[pswz(4 * tid + 0)] = y0;
    z[pswz(4 * tid + 1)] = y1;
    z[pswz(4 * tid + 2)] = y2;
    z[pswz(4 * tid + 3)] = y3;
    __syncthreads();

    // conjugate partner: tp = drev8((256 - r) & 255), r = drev8(tid)
    const int r  = drev8(tid);
    const int rm = (256 - r) & 255;
    const int tp = drev8(rm);
    double2 w3 = z[pswz(4 * tp + 3)];   // bin 768+rm = 1024-r   (r>0)
    double2 w2 = z[pswz(4 * tp + 2)];   // bin 512+rm = 768-r    (r>0)
    if (tid == 0) { w3 = y0; w2 = y3; } // r=0: mirrors are bins 0 and 768

    float* omag = out + (size_t)b * CUT * T_FRAMES;
    float* oph  = omag + (size_t)BATCH * CUT * T_FRAMES;

    // unpack + write bins k1 = r and k2 = 256 + r
    {
        float arf = (float)(0.5 * (y0.x + w3.x));
        float aif = (float)(0.5 * (y0.y - w3.y));
        size_t g = (size_t)r * T_FRAMES + (size_t)t0;
        omag[g] = sqrtf(arf * arf + aif * aif);
        oph[g]  = atan2f(aif, arf);
        if (has_b) {
            float brf = (float)(0.5 * (y0.y + w3.y));
            float bif = (float)(0.5 * (w3.x - y0.x));
            omag[g + 1] = sqrtf(brf * brf + bif * bif);
            oph[g + 1]  = atan2f(bif, brf);
        }
    }
    {
        float arf = (float)(0.5 * (y1.x + w2.x));
        float aif = (float)(0.5 * (y1.y - w2.y));
        size_t g = (size_t)(256 + r) * T_FRAMES + (size_t)t0;
        omag[g] = sqrtf(arf * arf + aif * aif);
        oph[g]  = atan2f(aif, arf);
        if (has_b) {
            float brf = (float)(0.5 * (y1.y + w2.y));
            float bif = (float)(0.5 * (w2.x - y1.x));
            omag[g + 1] = sqrtf(brf * brf + bif * bif);
            oph[g + 1]  = atan2f(bif, brf);
        }
    }
    // bin 512: real from FFT (thread 0 holds it in y2), imag from the dots
    if (tid == 0) {
        float iA = redIA[0] + redIA[1] + redIA[2] + redIA[3];
        float rf = (float)y2.x;
        size_t g = (size_t)512 * T_FRAMES + (size_t)t0;
        omag[g] = sqrtf(rf * rf + iA * iA);
        oph[g]  = atan2f(iA, rf);
        if (has_b) {
            float iB = redIB[0] + redIB[1] + redIB[2] + redIB[3];
            float rf2 = (float)y2.y;
            omag[g + 1] = sqrtf(rf2 * rf2 + iB * iB);
            oph[g + 1]  = atan2f(iB, rf2);
        }
    }
}

extern "C" void kernel_launch(void* const* d_in, const int* in_sizes, int n_in,
                              void* d_out, int out_size, void* d_ws, size_t ws_size,
                              hipStream_t stream) {
    (void)in_sizes; (void)n_in; (void)d_ws; (void)ws_size; (void)out_size;
    const float* x     = (const float*)d_in[0];
    const float* basis = (const float*)d_in[1];
    float* out = (float*)d_out;
    dim3 grid(NWG);     // 8176
    dim3 block(256);
    stft_fft_kernel<<<grid, block, 0, stream>>>(x, basis, out);
}